// Round 1
// baseline (144.656 us; speedup 1.0000x reference)
//
#include <hip/hip_runtime.h>
#include <stdint.h>

#define B_ 4
#define S_ 4096
#define D_ 128
#define KVB 64
#define NT (S_ / KVB)

typedef __bf16 bf16;
typedef __bf16 bf16x8 __attribute__((ext_vector_type(8)));
typedef float f32x4 __attribute__((ext_vector_type(4)));

// ws layout (bytes)
#define WBF_OFF 0
#define QB_OFF  131072
#define KB_OFF  (QB_OFF + B_*S_*D_*2)
#define VTB_OFF (KB_OFF + B_*S_*D_*2)

// ---------------------------------------------------------------- W -> bf16
__global__ __launch_bounds__(256) void wconv_kernel(const float* __restrict__ wq,
    const float* __restrict__ wk, const float* __restrict__ wv,
    bf16* __restrict__ wbf) {
  int i = blockIdx.x * 256 + threadIdx.x;            // 0..49151
  const float* src = (i < 16384) ? wq : (i < 32768 ? wk : wv);
  wbf[i] = (bf16)src[i & 16383];
}

// ------------------------------------------------- QKV projection (bf16 MFMA)
// q = x@Wq^T etc.  A = x[16x32-step], B[k=d][col=e] = W[e][d] (contig in d).
// Writes q,k row-major bf16; v transposed to [B][D][S] via LDS tile transpose.
__global__ __launch_bounds__(256) void proj_kernel(const float* __restrict__ x,
    const bf16* __restrict__ wbf, bf16* __restrict__ qb, bf16* __restrict__ kb,
    bf16* __restrict__ vtb) {
  __shared__ bf16 vtile[64][130];                    // +2 pad: conflict break
  const int tid  = threadIdx.x;
  const int wave = tid >> 6, lane = tid & 63;
  const int lrow = lane & 15, g = lane >> 4;
  const int row0b = blockIdx.x * 64;                 // block row base (64 rows)
  const int row0  = row0b + wave * 16;               // wave row base

  // A fragments: x rows, 8 contiguous d per lane, 4 k-steps
  bf16x8 af[4];
  {
    const float* xp = x + (size_t)(row0 + lrow) * D_ + g * 8;
#pragma unroll
    for (int ks = 0; ks < 4; ++ks) {
      const float4* p4 = (const float4*)(xp + ks * 32);
      float4 a0 = p4[0], a1 = p4[1];
      bf16x8 v;
      v[0]=(bf16)a0.x; v[1]=(bf16)a0.y; v[2]=(bf16)a0.z; v[3]=(bf16)a0.w;
      v[4]=(bf16)a1.x; v[5]=(bf16)a1.y; v[6]=(bf16)a1.z; v[7]=(bf16)a1.w;
      af[ks] = v;
    }
  }

  for (int m = 0; m < 3; ++m) {
    f32x4 acc[8];
#pragma unroll
    for (int c = 0; c < 8; ++c) acc[c] = (f32x4){0.f, 0.f, 0.f, 0.f};
#pragma unroll
    for (int c = 0; c < 8; ++c) {
#pragma unroll
      for (int ks = 0; ks < 4; ++ks) {
        bf16x8 bf = *(const bf16x8*)(wbf + m * 16384 +
                                     (size_t)(c * 16 + lrow) * D_ + ks * 32 + g * 8);
        acc[c] = __builtin_amdgcn_mfma_f32_16x16x32_bf16(af[ks], bf, acc[c], 0, 0, 0);
      }
    }
    if (m < 2) {
      bf16* ob = (m == 0) ? qb : kb;
#pragma unroll
      for (int c = 0; c < 8; ++c)
#pragma unroll
        for (int r = 0; r < 4; ++r)
          ob[(size_t)(row0 + g * 4 + r) * D_ + c * 16 + lrow] = (bf16)acc[c][r];
    } else {
      // v: stage C-tile to LDS, then write transposed (coalesced along s)
#pragma unroll
      for (int c = 0; c < 8; ++c)
#pragma unroll
        for (int r = 0; r < 4; ++r)
          vtile[wave * 16 + g * 4 + r][c * 16 + lrow] = (bf16)acc[c][r];
      __syncthreads();
      const int e = tid >> 1, h = tid & 1;
      const int b = row0b / S_;
      const int sb = (row0b & (S_ - 1)) + h * 32;
      bf16* vp = vtb + (size_t)(b * D_ + e) * S_ + sb;
#pragma unroll
      for (int j8 = 0; j8 < 4; ++j8) {
        bf16x8 v;
#pragma unroll
        for (int j = 0; j < 8; ++j) v[j] = vtile[h * 32 + j8 * 8 + j][e];
        *(bf16x8*)(vp + j8 * 8) = v;
      }
    }
  }
}

// ------------------------------------------------------------ flash attention
// grid (S/64, B); 4 waves x 16 q-rows. K tile [64][128] and V^T tile [128][64]
// double-buffered in LDS with 16B-chunk XOR swizzle; P via per-wave swizzled
// LDS; online softmax in raw-z space with exp2 (scale log2e/128).
__device__ __forceinline__ void stage_tiles(const bf16* __restrict__ kp,
                                            const bf16* __restrict__ vp,
                                            bf16* __restrict__ Ktb,
                                            bf16* __restrict__ Vtb, int tid) {
#pragma unroll
  for (int it = 0; it < 4; ++it) {                   // K: 64 rows x 256B
    int slot = it * 256 + tid;
    int row = slot >> 4, ch = slot & 15;
    bf16x8 v = *(const bf16x8*)(kp + (size_t)row * D_ + ch * 8);
    *(bf16x8*)(Ktb + row * 128 + ((ch ^ (row & 15)) * 8)) = v;
  }
#pragma unroll
  for (int it = 0; it < 4; ++it) {                   // V^T: 128 rows x 128B
    int slot = it * 256 + tid;
    int d = slot >> 3, ch = slot & 7;
    bf16x8 v = *(const bf16x8*)(vp + (size_t)d * S_ + ch * 8);
    *(bf16x8*)(Vtb + d * 64 + ((ch ^ (d & 7)) * 8)) = v;
  }
}

__global__ __launch_bounds__(256) void attn_kernel(const bf16* __restrict__ qb,
    const bf16* __restrict__ kb, const bf16* __restrict__ vtb,
    float* __restrict__ out) {
  __shared__ __align__(16) bf16 Kt[2][64 * 128];
  __shared__ __align__(16) bf16 Vt[2][128 * 64];
  __shared__ __align__(16) bf16 Pb[4][16 * 64];

  const int tid  = threadIdx.x;
  const int wave = tid >> 6, lane = tid & 63;
  const int lrow = lane & 15, g = lane >> 4;
  const int b  = blockIdx.y;
  const int q0 = blockIdx.x * 64;
  const float SC = 1.4426950408889634f / 128.0f;     // log2(e)/D

  bf16x8 qf[4];
  {
    const bf16* qp = qb + (size_t)(b * S_ + q0 + wave * 16 + lrow) * D_ + g * 8;
#pragma unroll
    for (int ks = 0; ks < 4; ++ks) qf[ks] = *(const bf16x8*)(qp + ks * 32);
  }

  f32x4 acc[8];
#pragma unroll
  for (int c = 0; c < 8; ++c) acc[c] = (f32x4){0.f, 0.f, 0.f, 0.f};
  float m_r[4] = {-1e30f, -1e30f, -1e30f, -1e30f};
  float l_r[4] = {0.f, 0.f, 0.f, 0.f};

  const bf16* kbase = kb + (size_t)b * S_ * D_;
  const bf16* vbase = vtb + (size_t)b * D_ * S_;

  stage_tiles(kbase, vbase, Kt[0], Vt[0], tid);
  __syncthreads();

  for (int t = 0; t < NT; ++t) {
    const int cur = t & 1;
    if (t + 1 < NT)
      stage_tiles(kbase + (size_t)(t + 1) * KVB * D_, vbase + (t + 1) * KVB,
                  Kt[cur ^ 1], Vt[cur ^ 1], tid);

    // ---- S = Q K^T (raw z)
    f32x4 s[4];
#pragma unroll
    for (int ti = 0; ti < 4; ++ti) {
      s[ti] = (f32x4){0.f, 0.f, 0.f, 0.f};
#pragma unroll
      for (int ks = 0; ks < 4; ++ks) {
        int row = ti * 16 + lrow;
        int ch = ks * 4 + g;
        bf16x8 kf = *(const bf16x8*)(&Kt[cur][row * 128 + ((ch ^ (row & 15)) * 8)]);
        s[ti] = __builtin_amdgcn_mfma_f32_16x16x32_bf16(qf[ks], kf, s[ti], 0, 0, 0);
      }
    }
    // ---- online softmax (rows g*4+r, reduce across 16-lane group)
    float tm[4];
#pragma unroll
    for (int r = 0; r < 4; ++r)
      tm[r] = fmaxf(fmaxf(s[0][r], s[1][r]), fmaxf(s[2][r], s[3][r]));
#pragma unroll
    for (int off = 1; off < 16; off <<= 1)
#pragma unroll
      for (int r = 0; r < 4; ++r)
        tm[r] = fmaxf(tm[r], __shfl_xor(tm[r], off));

    float al[4], ps[4];
#pragma unroll
    for (int r = 0; r < 4; ++r) {
      float mn = fmaxf(m_r[r], tm[r]);
      al[r] = __builtin_amdgcn_exp2f((m_r[r] - mn) * SC);
      m_r[r] = mn;
      ps[r] = 0.f;
    }
#pragma unroll
    for (int ti = 0; ti < 4; ++ti)
#pragma unroll
      for (int r = 0; r < 4; ++r) {
        float p = __builtin_amdgcn_exp2f((s[ti][r] - m_r[r]) * SC);
        ps[r] += p;
        int q = g * 4 + r, kv = ti * 16 + lrow, ch = kv >> 3;
        Pb[wave][q * 64 + ((ch ^ (q & 7)) * 8) + (kv & 7)] = (bf16)p;
      }
#pragma unroll
    for (int off = 1; off < 16; off <<= 1)
#pragma unroll
      for (int r = 0; r < 4; ++r)
        ps[r] += __shfl_xor(ps[r], off);
#pragma unroll
    for (int r = 0; r < 4; ++r) l_r[r] = l_r[r] * al[r] + ps[r];
#pragma unroll
    for (int c = 0; c < 8; ++c)
#pragma unroll
      for (int r = 0; r < 4; ++r) acc[c][r] *= al[r];

    // ---- O += P V
    bf16x8 pa[2];
#pragma unroll
    for (int k2 = 0; k2 < 2; ++k2) {
      int ch = k2 * 4 + g;
      pa[k2] = *(const bf16x8*)(&Pb[wave][lrow * 64 + ((ch ^ (lrow & 7)) * 8)]);
    }
#pragma unroll
    for (int c = 0; c < 8; ++c) {
#pragma unroll
      for (int k2 = 0; k2 < 2; ++k2) {
        int d = c * 16 + lrow;
        int ch = k2 * 4 + g;
        bf16x8 vf = *(const bf16x8*)(&Vt[cur][d * 64 + ((ch ^ (d & 7)) * 8)]);
        acc[c] = __builtin_amdgcn_mfma_f32_16x16x32_bf16(pa[k2], vf, acc[c], 0, 0, 0);
      }
    }
    __syncthreads();   // staged tile ready; all waves done with cur buffer
  }

  float inv[4];
#pragma unroll
  for (int r = 0; r < 4; ++r) inv[r] = 1.0f / l_r[r];
#pragma unroll
  for (int c = 0; c < 8; ++c)
#pragma unroll
    for (int r = 0; r < 4; ++r) {
      int row = q0 + wave * 16 + g * 4 + r;
      out[(size_t)(b * S_ + row) * D_ + c * 16 + lrow] = acc[c][r] * inv[r];
    }
}

// ---------------------------------------------------------------------------
extern "C" void kernel_launch(void* const* d_in, const int* in_sizes, int n_in,
                              void* d_out, int out_size, void* d_ws, size_t ws_size,
                              hipStream_t stream) {
  const float* x  = (const float*)d_in[0];
  const float* wq = (const float*)d_in[1];
  const float* wk = (const float*)d_in[2];
  const float* wv = (const float*)d_in[3];
  float* out = (float*)d_out;
  char* ws = (char*)d_ws;
  bf16* wbf = (bf16*)(ws + WBF_OFF);
  bf16* qb  = (bf16*)(ws + QB_OFF);
  bf16* kb  = (bf16*)(ws + KB_OFF);
  bf16* vtb = (bf16*)(ws + VTB_OFF);

  hipLaunchKernelGGL(wconv_kernel, dim3(192), dim3(256), 0, stream, wq, wk, wv, wbf);
  hipLaunchKernelGGL(proj_kernel, dim3(256), dim3(256), 0, stream, x, wbf, qb, kb, vtb);
  hipLaunchKernelGGL(attn_kernel, dim3(64, 4), dim3(256), 0, stream, qb, kb, vtb, out);
}

// Round 2
// 144.440 us; speedup vs baseline: 1.0015x; 1.0015x over previous
//
#include <hip/hip_runtime.h>
#include <stdint.h>

#define B_ 4
#define S_ 4096
#define D_ 128
#define KVB 32
#define NT (S_ / KVB)
#define NR (B_ * S_)

typedef __bf16 bf16;
typedef __bf16 bf16x8 __attribute__((ext_vector_type(8)));
typedef float f32x4 __attribute__((ext_vector_type(4)));

// ws layout (bytes)
#define WBF_OFF 0
#define QB_OFF  131072
#define KB_OFF  (QB_OFF + B_*S_*D_*2)
#define VTB_OFF (KB_OFF + B_*S_*D_*2)
#define ACC_OFF (VTB_OFF + B_*S_*D_*2)          // 12713984

#define GLOAD_LDS16(g, l)                                                    \
  __builtin_amdgcn_global_load_lds(                                          \
      (const __attribute__((address_space(1))) void*)(g),                    \
      (__attribute__((address_space(3))) void*)(l), 16, 0, 0)

// ---------------------------------------------------------------- W -> bf16
__global__ __launch_bounds__(256) void wconv_kernel(const float* __restrict__ wq,
    const float* __restrict__ wk, const float* __restrict__ wv,
    bf16* __restrict__ wbf) {
  int i = blockIdx.x * 256 + threadIdx.x;            // 0..49151
  const float* src = (i < 16384) ? wq : (i < 32768 ? wk : wv);
  wbf[i] = (bf16)src[i & 16383];
}

// ------------------------------------------------- QKV projection (bf16 MFMA)
__global__ __launch_bounds__(256) void proj_kernel(const float* __restrict__ x,
    const bf16* __restrict__ wbf, bf16* __restrict__ qb, bf16* __restrict__ kb,
    bf16* __restrict__ vtb) {
  __shared__ bf16 vtile[64][130];
  const int tid  = threadIdx.x;
  const int wave = tid >> 6, lane = tid & 63;
  const int lrow = lane & 15, g = lane >> 4;
  const int row0b = blockIdx.x * 64;
  const int row0  = row0b + wave * 16;

  bf16x8 af[4];
  {
    const float* xp = x + (size_t)(row0 + lrow) * D_ + g * 8;
#pragma unroll
    for (int ks = 0; ks < 4; ++ks) {
      const float4* p4 = (const float4*)(xp + ks * 32);
      float4 a0 = p4[0], a1 = p4[1];
      bf16x8 v;
      v[0]=(bf16)a0.x; v[1]=(bf16)a0.y; v[2]=(bf16)a0.z; v[3]=(bf16)a0.w;
      v[4]=(bf16)a1.x; v[5]=(bf16)a1.y; v[6]=(bf16)a1.z; v[7]=(bf16)a1.w;
      af[ks] = v;
    }
  }

  for (int m = 0; m < 3; ++m) {
    f32x4 acc[8];
#pragma unroll
    for (int c = 0; c < 8; ++c) acc[c] = (f32x4){0.f, 0.f, 0.f, 0.f};
#pragma unroll
    for (int c = 0; c < 8; ++c) {
#pragma unroll
      for (int ks = 0; ks < 4; ++ks) {
        bf16x8 bf = *(const bf16x8*)(wbf + m * 16384 +
                                     (size_t)(c * 16 + lrow) * D_ + ks * 32 + g * 8);
        acc[c] = __builtin_amdgcn_mfma_f32_16x16x32_bf16(af[ks], bf, acc[c], 0, 0, 0);
      }
    }
    if (m < 2) {
      bf16* ob = (m == 0) ? qb : kb;
#pragma unroll
      for (int c = 0; c < 8; ++c)
#pragma unroll
        for (int r = 0; r < 4; ++r)
          ob[(size_t)(row0 + g * 4 + r) * D_ + c * 16 + lrow] = (bf16)acc[c][r];
    } else {
#pragma unroll
      for (int c = 0; c < 8; ++c)
#pragma unroll
        for (int r = 0; r < 4; ++r)
          vtile[wave * 16 + g * 4 + r][c * 16 + lrow] = (bf16)acc[c][r];
      __syncthreads();
      const int e = tid >> 1, h = tid & 1;
      const int b = row0b / S_;
      const int sb = (row0b & (S_ - 1)) + h * 32;
      bf16* vp = vtb + (size_t)(b * D_ + e) * S_ + sb;
#pragma unroll
      for (int j8 = 0; j8 < 4; ++j8) {
        bf16x8 v;
#pragma unroll
        for (int j = 0; j < 8; ++j) v[j] = vtile[h * 32 + j8 * 8 + j][e];
        *(bf16x8*)(vp + j8 * 8) = v;
      }
    }
  }
}

// ------------------------------------------------------------ flash attention
// grid (S/64, B, NS); 4 waves x 16 q-rows, KVB=32, KV-split across blockIdx.z.
// K [32][128] / V^T [128][32] double-buffered, staged via global_load_lds with
// pre-swizzled (inverse-XOR) global source addresses; LDS stays linear-dest.
__device__ __forceinline__ void stage_tiles(const bf16* __restrict__ kp,
                                            const bf16* __restrict__ vp,
                                            bf16* __restrict__ Ktb,
                                            bf16* __restrict__ Vtb,
                                            int wave, int lane) {
#pragma unroll
  for (int it = 0; it < 2; ++it) {                   // K: 8KB, 512 chunks
    int ci = (wave * 2 + it) * 64 + lane;
    int row = ci >> 4, pos = ci & 15;
    int ch = pos ^ (row & 15);
    GLOAD_LDS16(kp + (size_t)row * D_ + ch * 8, Ktb + ci * 8 - lane * 8);
  }
#pragma unroll
  for (int it = 0; it < 2; ++it) {                   // V^T: 8KB, 512 chunks
    int ci = (wave * 2 + it) * 64 + lane;
    int d = ci >> 2, pos = ci & 3;
    int ch = pos ^ ((d ^ (d >> 2)) & 3);
    GLOAD_LDS16(vp + (size_t)d * S_ + ch * 8, Vtb + ci * 8 - lane * 8);
  }
}

__global__ __launch_bounds__(256, 4) void attn_kernel(const bf16* __restrict__ qb,
    const bf16* __restrict__ kb, const bf16* __restrict__ vtb,
    float* __restrict__ out, float* __restrict__ accP, float* __restrict__ ml) {
  __shared__ __align__(16) bf16 Kt[2][KVB * 128];    // 2 x 8KB
  __shared__ __align__(16) bf16 Vt[2][128 * KVB];    // 2 x 8KB
  __shared__ __align__(16) bf16 Pb[4][16 * KVB];     // 4KB

  const int tid  = threadIdx.x;
  const int wave = tid >> 6, lane = tid & 63;
  const int lrow = lane & 15, g = lane >> 4;
  const int b  = blockIdx.y;
  const int q0 = blockIdx.x * 64;
  const int ns = gridDim.z, seg = blockIdx.z;
  const int ntseg = NT / ns;
  const float SC = 1.4426950408889634f / 128.0f;     // log2(e)/D

  bf16x8 qf[4];
  {
    const bf16* qp = qb + (size_t)(b * S_ + q0 + wave * 16 + lrow) * D_ + g * 8;
#pragma unroll
    for (int ks = 0; ks < 4; ++ks) qf[ks] = *(const bf16x8*)(qp + ks * 32);
  }

  f32x4 acc[8];
#pragma unroll
  for (int c = 0; c < 8; ++c) acc[c] = (f32x4){0.f, 0.f, 0.f, 0.f};
  float m_r[4] = {-1e30f, -1e30f, -1e30f, -1e30f};
  float l_r[4] = {0.f, 0.f, 0.f, 0.f};

  const bf16* kbase = kb + ((size_t)b * S_ + (size_t)seg * ntseg * KVB) * D_;
  const bf16* vbase = vtb + (size_t)b * D_ * S_ + (size_t)seg * ntseg * KVB;

  stage_tiles(kbase, vbase, Kt[0], Vt[0], wave, lane);
  __syncthreads();

  for (int t = 0; t < ntseg; ++t) {
    const int cur = t & 1;
    if (t + 1 < ntseg)
      stage_tiles(kbase + (size_t)(t + 1) * KVB * D_, vbase + (t + 1) * KVB,
                  Kt[cur ^ 1], Vt[cur ^ 1], wave, lane);

    // ---- S = Q K^T (raw z)
    f32x4 s[2];
#pragma unroll
    for (int ti = 0; ti < 2; ++ti) {
      s[ti] = (f32x4){0.f, 0.f, 0.f, 0.f};
#pragma unroll
      for (int ks = 0; ks < 4; ++ks) {
        int row = ti * 16 + lrow;
        int ch = ks * 4 + g;
        bf16x8 kf = *(const bf16x8*)(&Kt[cur][row * 128 + ((ch ^ (row & 15)) * 8)]);
        s[ti] = __builtin_amdgcn_mfma_f32_16x16x32_bf16(qf[ks], kf, s[ti], 0, 0, 0);
      }
    }
    // ---- online softmax
    float tm[4];
#pragma unroll
    for (int r = 0; r < 4; ++r) tm[r] = fmaxf(s[0][r], s[1][r]);
#pragma unroll
    for (int off = 1; off < 16; off <<= 1)
#pragma unroll
      for (int r = 0; r < 4; ++r)
        tm[r] = fmaxf(tm[r], __shfl_xor(tm[r], off));

    float al[4], ps[4];
#pragma unroll
    for (int r = 0; r < 4; ++r) {
      float mn = fmaxf(m_r[r], tm[r]);
      al[r] = __builtin_amdgcn_exp2f((m_r[r] - mn) * SC);
      m_r[r] = mn;
      ps[r] = 0.f;
    }
#pragma unroll
    for (int ti = 0; ti < 2; ++ti)
#pragma unroll
      for (int r = 0; r < 4; ++r) {
        float p = __builtin_amdgcn_exp2f((s[ti][r] - m_r[r]) * SC);
        ps[r] += p;
        int q = g * 4 + r, kv = ti * 16 + lrow, ch = kv >> 3;
        Pb[wave][q * KVB + ((ch ^ ((q ^ (q >> 2)) & 3)) * 8) + (kv & 7)] = (bf16)p;
      }
#pragma unroll
    for (int off = 1; off < 16; off <<= 1)
#pragma unroll
      for (int r = 0; r < 4; ++r)
        ps[r] += __shfl_xor(ps[r], off);
#pragma unroll
    for (int r = 0; r < 4; ++r) l_r[r] = l_r[r] * al[r] + ps[r];
#pragma unroll
    for (int c = 0; c < 8; ++c)
#pragma unroll
      for (int r = 0; r < 4; ++r) acc[c][r] *= al[r];

    // ---- O += P V
    bf16x8 pa = *(const bf16x8*)(
        &Pb[wave][lrow * KVB + ((g ^ ((lrow ^ (lrow >> 2)) & 3)) * 8)]);
#pragma unroll
    for (int c = 0; c < 8; ++c) {
      int d = c * 16 + lrow;
      bf16x8 vf = *(const bf16x8*)(
          &Vt[cur][d * KVB + ((g ^ ((d ^ (d >> 2)) & 3)) * 8)]);
      acc[c] = __builtin_amdgcn_mfma_f32_16x16x32_bf16(pa, vf, acc[c], 0, 0, 0);
    }
    __syncthreads();
  }

  if (gridDim.z == 1) {
    float inv[4];
#pragma unroll
    for (int r = 0; r < 4; ++r) inv[r] = 1.0f / l_r[r];
#pragma unroll
    for (int c = 0; c < 8; ++c)
#pragma unroll
      for (int r = 0; r < 4; ++r) {
        int row = q0 + wave * 16 + g * 4 + r;
        out[(size_t)(b * S_ + row) * D_ + c * 16 + lrow] = acc[c][r] * inv[r];
      }
  } else {
#pragma unroll
    for (int c = 0; c < 8; ++c)
#pragma unroll
      for (int r = 0; r < 4; ++r) {
        int row = b * S_ + q0 + wave * 16 + g * 4 + r;
        accP[(((size_t)seg * NR + row) << 7) + c * 16 + lrow] = acc[c][r];
      }
    if (lrow == 0)
#pragma unroll
      for (int r = 0; r < 4; ++r) {
        int row = b * S_ + q0 + wave * 16 + g * 4 + r;
        ml[((size_t)seg * NR + row) * 2]     = m_r[r];
        ml[((size_t)seg * NR + row) * 2 + 1] = l_r[r];
      }
  }
}

// --------------------------------------------------------------- combine pass
__global__ __launch_bounds__(256) void combine_kernel(const float* __restrict__ accP,
    const float* __restrict__ ml, float* __restrict__ out, int ns) {
  const int row = blockIdx.x * 2 + (threadIdx.x >> 7);
  const int d = threadIdx.x & 127;
  const float SC = 1.4426950408889634f / 128.0f;
  float M = -3e38f;
  for (int i = 0; i < ns; ++i) M = fmaxf(M, ml[((size_t)i * NR + row) * 2]);
  float L = 0.f, o = 0.f;
  for (int i = 0; i < ns; ++i) {
    float mi = ml[((size_t)i * NR + row) * 2];
    float li = ml[((size_t)i * NR + row) * 2 + 1];
    float w = __builtin_amdgcn_exp2f((mi - M) * SC);
    L += w * li;
    o += w * accP[(((size_t)i * NR + row) << 7) + d];
  }
  out[(size_t)row * 128 + d] = o / L;
}

// ---------------------------------------------------------------------------
extern "C" void kernel_launch(void* const* d_in, const int* in_sizes, int n_in,
                              void* d_out, int out_size, void* d_ws, size_t ws_size,
                              hipStream_t stream) {
  const float* x  = (const float*)d_in[0];
  const float* wq = (const float*)d_in[1];
  const float* wk = (const float*)d_in[2];
  const float* wv = (const float*)d_in[3];
  float* out = (float*)d_out;
  char* ws = (char*)d_ws;
  bf16* wbf = (bf16*)(ws + WBF_OFF);
  bf16* qb  = (bf16*)(ws + QB_OFF);
  bf16* kb  = (bf16*)(ws + KB_OFF);
  bf16* vtb = (bf16*)(ws + VTB_OFF);

  const size_t acc1 = (size_t)NR * D_ * 4;           // 8 MB per segment
  const size_t ml1  = (size_t)NR * 8;
  int ns = 4;
  if (ws_size < ACC_OFF + 4 * (acc1 + ml1)) ns = 2;
  if (ws_size < ACC_OFF + 2 * (acc1 + ml1)) ns = 1;
  float* accP = (float*)(ws + ACC_OFF);
  float* mlp  = (float*)(ws + ACC_OFF + (size_t)ns * acc1);

  hipLaunchKernelGGL(wconv_kernel, dim3(192), dim3(256), 0, stream, wq, wk, wv, wbf);
  hipLaunchKernelGGL(proj_kernel, dim3(256), dim3(256), 0, stream, x, wbf, qb, kb, vtb);
  hipLaunchKernelGGL(attn_kernel, dim3(64, B_, ns), dim3(256), 0, stream,
                     qb, kb, vtb, out, accP, mlp);
  if (ns > 1)
    hipLaunchKernelGGL(combine_kernel, dim3(NR / 2), dim3(256), 0, stream,
                       accP, mlp, out, ns);
}

// Round 3
// 83.003 us; speedup vs baseline: 1.7428x; 1.7402x over previous
//
#include <hip/hip_runtime.h>
#include <stdint.h>

#define B_ 4
#define S_ 4096
#define D_ 128
#define KVB 64
#define NT (S_ / KVB)
#define NR (B_ * S_)

typedef __bf16 bf16;
typedef __bf16 bf16x4 __attribute__((ext_vector_type(4)));
typedef __bf16 bf16x8 __attribute__((ext_vector_type(8)));
typedef float f32x4 __attribute__((ext_vector_type(4)));

// ws layout (bytes)
#define WBF_OFF 0
#define QB_OFF  131072
#define KB_OFF  (QB_OFF + B_*S_*D_*2)
#define VTB_OFF (KB_OFF + B_*S_*D_*2)
#define ACC_OFF (VTB_OFF + B_*S_*D_*2)          // 12713984

#define GLOAD_LDS16(g, l)                                                    \
  __builtin_amdgcn_global_load_lds(                                          \
      (const __attribute__((address_space(1))) void*)(g),                    \
      (__attribute__((address_space(3))) void*)(l), 16, 0, 0)

// ---------------------------------------------------------------- W -> bf16
__global__ __launch_bounds__(256) void wconv_kernel(const float* __restrict__ wq,
    const float* __restrict__ wk, const float* __restrict__ wv,
    bf16* __restrict__ wbf) {
  int i = blockIdx.x * 256 + threadIdx.x;            // 0..49151
  const float* src = (i < 16384) ? wq : (i < 32768 ? wk : wv);
  wbf[i] = (bf16)src[i & 16383];
}

// ------------------------------------------------- QKV projection (bf16 MFMA)
// Writes q,k row-major bf16. V is written transposed [B][D][S] AND, within
// each 32-kv block, kappa-interleaved: position p = g*8 + ti*4 + r holds
// kv = ti*16 + g*4 + r  (so attn PV B-frags are single contiguous 16B chunks).
__global__ __launch_bounds__(256) void proj_kernel(const float* __restrict__ x,
    const bf16* __restrict__ wbf, bf16* __restrict__ qb, bf16* __restrict__ kb,
    bf16* __restrict__ vtb) {
  __shared__ bf16 vtile[64][130];
  const int tid  = threadIdx.x;
  const int wave = tid >> 6, lane = tid & 63;
  const int lrow = lane & 15, g = lane >> 4;
  const int row0b = blockIdx.x * 64;
  const int row0  = row0b + wave * 16;

  bf16x8 af[4];
  {
    const float* xp = x + (size_t)(row0 + lrow) * D_ + g * 8;
#pragma unroll
    for (int ks = 0; ks < 4; ++ks) {
      const float4* p4 = (const float4*)(xp + ks * 32);
      float4 a0 = p4[0], a1 = p4[1];
      bf16x8 v;
      v[0]=(bf16)a0.x; v[1]=(bf16)a0.y; v[2]=(bf16)a0.z; v[3]=(bf16)a0.w;
      v[4]=(bf16)a1.x; v[5]=(bf16)a1.y; v[6]=(bf16)a1.z; v[7]=(bf16)a1.w;
      af[ks] = v;
    }
  }

  for (int m = 0; m < 3; ++m) {
    f32x4 acc[8];
#pragma unroll
    for (int c = 0; c < 8; ++c) acc[c] = (f32x4){0.f, 0.f, 0.f, 0.f};
#pragma unroll
    for (int c = 0; c < 8; ++c) {
#pragma unroll
      for (int ks = 0; ks < 4; ++ks) {
        bf16x8 bf = *(const bf16x8*)(wbf + m * 16384 +
                                     (size_t)(c * 16 + lrow) * D_ + ks * 32 + g * 8);
        acc[c] = __builtin_amdgcn_mfma_f32_16x16x32_bf16(af[ks], bf, acc[c], 0, 0, 0);
      }
    }
    if (m < 2) {
      bf16* ob = (m == 0) ? qb : kb;
#pragma unroll
      for (int c = 0; c < 8; ++c)
#pragma unroll
        for (int r = 0; r < 4; ++r)
          ob[(size_t)(row0 + g * 4 + r) * D_ + c * 16 + lrow] = (bf16)acc[c][r];
    } else {
#pragma unroll
      for (int c = 0; c < 8; ++c)
#pragma unroll
        for (int r = 0; r < 4; ++r)
          vtile[wave * 16 + g * 4 + r][c * 16 + lrow] = (bf16)acc[c][r];
      __syncthreads();
      // thread (e,h): e = d-index 0..127, h selects one 32-kv block
      const int e = tid >> 1, h = tid & 1;
      const int b = row0b / S_;
      const int sb = (row0b & (S_ - 1)) + h * 32;
      bf16* vp = vtb + (size_t)(b * D_ + e) * S_ + sb;
#pragma unroll
      for (int pc = 0; pc < 8; ++pc) {                 // p-chunk of 4 positions
        int kvs = (pc & 1) * 16 + (pc >> 1) * 4;       // kv(p = pc*4)
        bf16x4 v;
#pragma unroll
        for (int i = 0; i < 4; ++i) v[i] = vtile[h * 32 + kvs + i][e];
        *(bf16x4*)(vp + pc * 4) = v;
      }
    }
  }
}

// ------------------------------------------------------------ flash attention
// grid (S/128, B, NS); 4 waves x 32 q-rows. Swapped QK^T (A=K,B=Q) keeps P
// lane-local; kappa-permuted PV consumes packed P directly from registers.
// K [64][128] (256B rows, 16-slot XOR) and Vpi [128][64] (128B rows, 8-slot
// XOR) double-buffered, staged via global_load_lds w/ pre-swizzled source.
__device__ __forceinline__ void stage_tiles(const bf16* __restrict__ kp,
                                            const bf16* __restrict__ vp,
                                            bf16* __restrict__ Ktb,
                                            bf16* __restrict__ Vtb,
                                            int wave, int lane) {
#pragma unroll
  for (int it = 0; it < 4; ++it) {                   // K: 16KB, 1024 chunks
    int ci = (wave * 4 + it) * 64 + lane;
    int row = ci >> 4, pos = ci & 15;
    int ch = pos ^ (row & 15);
    GLOAD_LDS16(kp + (size_t)row * D_ + ch * 8, Ktb + ci * 8 - lane * 8);
  }
#pragma unroll
  for (int it = 0; it < 4; ++it) {                   // Vpi: 16KB, 1024 chunks
    int ci = (wave * 4 + it) * 64 + lane;
    int d = ci >> 3, pos = ci & 7;
    int ch = pos ^ (d & 7);
    GLOAD_LDS16(vp + (size_t)d * S_ + ch * 8, Vtb + ci * 8 - lane * 8);
  }
}

__global__ __launch_bounds__(256, 2) void attn_kernel(const bf16* __restrict__ qb,
    const bf16* __restrict__ kb, const bf16* __restrict__ vtb,
    float* __restrict__ out, float* __restrict__ accP, float* __restrict__ ml) {
  __shared__ __align__(16) bf16 Kt[2][KVB * 128];    // 2 x 16KB
  __shared__ __align__(16) bf16 Vt[2][128 * KVB];    // 2 x 16KB

  const int tid  = threadIdx.x;
  const int wave = tid >> 6, lane = tid & 63;
  const int lrow = lane & 15, g = lane >> 4;
  const int b  = blockIdx.y;
  const int q0 = blockIdx.x * 128 + wave * 32;       // wave's 32 q-rows
  const int ns = gridDim.z, seg = blockIdx.z;
  const int ntseg = NT / ns;
  const float SC = 1.4426950408889634f / 128.0f;     // log2(e)/D
  const float THR = 512.0f;                          // defer-max threshold (raw z)

  // Q as B-frag: lane&15 = q col, k-slice d = ks*32 + g*8
  bf16x8 qf[2][4];
#pragma unroll
  for (int a = 0; a < 2; ++a) {
    const bf16* qp = qb + (size_t)(b * S_ + q0 + a * 16 + lrow) * D_ + g * 8;
#pragma unroll
    for (int ks = 0; ks < 4; ++ks) qf[a][ks] = *(const bf16x8*)(qp + ks * 32);
  }

  f32x4 acc[2][8];
#pragma unroll
  for (int a = 0; a < 2; ++a)
#pragma unroll
    for (int c = 0; c < 8; ++c) acc[a][c] = (f32x4){0.f, 0.f, 0.f, 0.f};
  float m_r[2] = {-1e30f, -1e30f};
  float l_r[2] = {0.f, 0.f};

  const bf16* kbase = kb + ((size_t)b * S_ + (size_t)seg * ntseg * KVB) * D_;
  const bf16* vbase = vtb + (size_t)b * D_ * S_ + (size_t)seg * ntseg * KVB;

  stage_tiles(kbase, vbase, Kt[0], Vt[0], wave, lane);
  __syncthreads();

  for (int t = 0; t < ntseg; ++t) {
    const int cur = t & 1;
    if (t + 1 < ntseg)
      stage_tiles(kbase + (size_t)(t + 1) * KVB * D_, vbase + (t + 1) * KVB,
                  Kt[cur ^ 1], Vt[cur ^ 1], wave, lane);

    // ---- S^T = K Q  : lane holds S[q=lane&15(+16a)][kv = ti*16 + g*4 + r]
    f32x4 s[2][4];
#pragma unroll
    for (int a = 0; a < 2; ++a)
#pragma unroll
      for (int ti = 0; ti < 4; ++ti) s[a][ti] = (f32x4){0.f, 0.f, 0.f, 0.f};
#pragma unroll
    for (int ti = 0; ti < 4; ++ti) {
#pragma unroll
      for (int ks = 0; ks < 4; ++ks) {
        const int row = ti * 16 + lrow;
        bf16x8 kf = *(const bf16x8*)(
            &Kt[cur][row * 128 + (((ks * 4 + g) ^ (row & 15)) * 8)]);
        s[0][ti] = __builtin_amdgcn_mfma_f32_16x16x32_bf16(kf, qf[0][ks], s[0][ti], 0, 0, 0);
        s[1][ti] = __builtin_amdgcn_mfma_f32_16x16x32_bf16(kf, qf[1][ks], s[1][ti], 0, 0, 0);
      }
    }

    // ---- tile max per q (in-register 16 + 2 shfl across g-lanes)
    float tmax[2];
#pragma unroll
    for (int a = 0; a < 2; ++a) {
      float t0 = fmaxf(fmaxf(s[a][0][0], s[a][0][1]), fmaxf(s[a][0][2], s[a][0][3]));
      float t1 = fmaxf(fmaxf(s[a][1][0], s[a][1][1]), fmaxf(s[a][1][2], s[a][1][3]));
      float t2 = fmaxf(fmaxf(s[a][2][0], s[a][2][1]), fmaxf(s[a][2][2], s[a][2][3]));
      float t3 = fmaxf(fmaxf(s[a][3][0], s[a][3][1]), fmaxf(s[a][3][2], s[a][3][3]));
      float tm = fmaxf(fmaxf(t0, t1), fmaxf(t2, t3));
      tm = fmaxf(tm, __shfl_xor(tm, 16));
      tm = fmaxf(tm, __shfl_xor(tm, 32));
      tmax[a] = tm;
    }

    // ---- defer-max: rescale only if some row grew past THR
    bool needs = (tmax[0] - m_r[0] > THR) || (tmax[1] - m_r[1] > THR);
    if (__any(needs)) {
#pragma unroll
      for (int a = 0; a < 2; ++a) {
        float mn = fmaxf(m_r[a], tmax[a]);
        float al = __builtin_amdgcn_exp2f((m_r[a] - mn) * SC);
        m_r[a] = mn;
        l_r[a] *= al;
        float alr[4];
#pragma unroll
        for (int r = 0; r < 4; ++r) alr[r] = __shfl(al, g * 4 + r);
#pragma unroll
        for (int c = 0; c < 8; ++c) {
          acc[a][c][0] *= alr[0]; acc[a][c][1] *= alr[1];
          acc[a][c][2] *= alr[2]; acc[a][c][3] *= alr[3];
        }
      }
    }

    // ---- P = exp2((s-m)*SC), row-sum, pack kappa-ordered A-frags in-lane
    float tsum[2] = {0.f, 0.f};
#pragma unroll
    for (int a = 0; a < 2; ++a)
#pragma unroll
      for (int ti = 0; ti < 4; ++ti)
#pragma unroll
        for (int r = 0; r < 4; ++r) {
          float e = __builtin_amdgcn_exp2f((s[a][ti][r] - m_r[a]) * SC);
          s[a][ti][r] = e;
          tsum[a] += e;
        }
#pragma unroll
    for (int a = 0; a < 2; ++a) {
      tsum[a] += __shfl_xor(tsum[a], 16);
      tsum[a] += __shfl_xor(tsum[a], 32);
      l_r[a] += tsum[a];
    }

    bf16x8 pa[2][2];
#pragma unroll
    for (int a = 0; a < 2; ++a)
#pragma unroll
      for (int bb = 0; bb < 2; ++bb) {
        bf16x8 v;
#pragma unroll
        for (int r = 0; r < 4; ++r) {
          v[r]     = (bf16)s[a][2 * bb][r];
          v[4 + r] = (bf16)s[a][2 * bb + 1][r];
        }
        pa[a][bb] = v;
      }

    // ---- O += P Vpi   (B-frag: single 16B chunk, kappa order matches)
#pragma unroll
    for (int c = 0; c < 8; ++c) {
      const int d = c * 16 + lrow;
#pragma unroll
      for (int bb = 0; bb < 2; ++bb) {
        bf16x8 vf = *(const bf16x8*)(
            &Vt[cur][d * KVB + (((bb * 4 + g) ^ (d & 7)) * 8)]);
        acc[0][c] = __builtin_amdgcn_mfma_f32_16x16x32_bf16(pa[0][bb], vf, acc[0][c], 0, 0, 0);
        acc[1][c] = __builtin_amdgcn_mfma_f32_16x16x32_bf16(pa[1][bb], vf, acc[1][c], 0, 0, 0);
      }
    }
    __syncthreads();
  }

  // ---- epilogue: divide by l (l lives at lane&15 == q; acc rows are g*4+r)
  if (ns == 1) {
#pragma unroll
    for (int a = 0; a < 2; ++a) {
      float linv[4];
#pragma unroll
      for (int r = 0; r < 4; ++r) linv[r] = 1.0f / __shfl(l_r[a], g * 4 + r);
#pragma unroll
      for (int c = 0; c < 8; ++c)
#pragma unroll
        for (int r = 0; r < 4; ++r) {
          int row = q0 + a * 16 + g * 4 + r;
          out[(size_t)(b * S_ + row) * D_ + c * 16 + lrow] = acc[a][c][r] * linv[r];
        }
    }
  } else {
#pragma unroll
    for (int a = 0; a < 2; ++a) {
#pragma unroll
      for (int c = 0; c < 8; ++c)
#pragma unroll
        for (int r = 0; r < 4; ++r) {
          int row = b * S_ + q0 + a * 16 + g * 4 + r;
          accP[(((size_t)seg * NR + row) << 7) + c * 16 + lrow] = acc[a][c][r];
        }
      if (g == 0) {
        int row = b * S_ + q0 + a * 16 + lrow;
        ml[((size_t)seg * NR + row) * 2]     = m_r[a];
        ml[((size_t)seg * NR + row) * 2 + 1] = l_r[a];
      }
    }
  }
}

// --------------------------------------------------------------- combine pass
__global__ __launch_bounds__(256) void combine_kernel(const float* __restrict__ accP,
    const float* __restrict__ ml, float* __restrict__ out, int ns) {
  const int row = blockIdx.x * 2 + (threadIdx.x >> 7);
  const int d = threadIdx.x & 127;
  const float SC = 1.4426950408889634f / 128.0f;
  float M = -3e38f;
  for (int i = 0; i < ns; ++i) M = fmaxf(M, ml[((size_t)i * NR + row) * 2]);
  float L = 0.f, o = 0.f;
  for (int i = 0; i < ns; ++i) {
    float mi = ml[((size_t)i * NR + row) * 2];
    float li = ml[((size_t)i * NR + row) * 2 + 1];
    float w = __builtin_amdgcn_exp2f((mi - M) * SC);
    L += w * li;
    o += w * accP[(((size_t)i * NR + row) << 7) + d];
  }
  out[(size_t)row * 128 + d] = o / L;
}

// ---------------------------------------------------------------------------
extern "C" void kernel_launch(void* const* d_in, const int* in_sizes, int n_in,
                              void* d_out, int out_size, void* d_ws, size_t ws_size,
                              hipStream_t stream) {
  const float* x  = (const float*)d_in[0];
  const float* wq = (const float*)d_in[1];
  const float* wk = (const float*)d_in[2];
  const float* wv = (const float*)d_in[3];
  float* out = (float*)d_out;
  char* ws = (char*)d_ws;
  bf16* wbf = (bf16*)(ws + WBF_OFF);
  bf16* qb  = (bf16*)(ws + QB_OFF);
  bf16* kb  = (bf16*)(ws + KB_OFF);
  bf16* vtb = (bf16*)(ws + VTB_OFF);

  const size_t acc1 = (size_t)NR * D_ * 4;           // 8 MB per segment
  const size_t ml1  = (size_t)NR * 8;
  int ns = 4;
  if (ws_size < ACC_OFF + 4 * (acc1 + ml1)) ns = 2;
  if (ws_size < ACC_OFF + 2 * (acc1 + ml1)) ns = 1;
  float* accP = (float*)(ws + ACC_OFF);
  float* mlp  = (float*)(ws + ACC_OFF + (size_t)ns * acc1);

  hipLaunchKernelGGL(wconv_kernel, dim3(192), dim3(256), 0, stream, wq, wk, wv, wbf);
  hipLaunchKernelGGL(proj_kernel, dim3(256), dim3(256), 0, stream, x, wbf, qb, kb, vtb);
  hipLaunchKernelGGL(attn_kernel, dim3(S_ / 128, B_, ns), dim3(256), 0, stream,
                     qb, kb, vtb, out, accP, mlp);
  if (ns > 1)
    hipLaunchKernelGGL(combine_kernel, dim3(NR / 2), dim3(256), 0, stream,
                       accP, mlp, out, ns);
}